// Round 1
// baseline (191.575 us; speedup 1.0000x reference)
//
#include <hip/hip_runtime.h>
#include <hip/hip_bf16.h>

#define Bb 4
#define Ss 512
#define Hh 768
#define Dd 24
#define Mm 96
#define Oo 768

typedef __bf16 bf16x8 __attribute__((ext_vector_type(8)));
typedef float f32x4 __attribute__((ext_vector_type(4)));

// ---------------------------------------------------------------------------
// Transpose tile helper: dst[c][r] = bf16(src[r][c]), one 32x32 tile.
// ---------------------------------------------------------------------------
__device__ __forceinline__ void transpose_tile(
    const float* __restrict__ s, __bf16* __restrict__ d,
    int R, int C, int bx, int by, float* smem, int tid)
{
    // smem used as t[32][33]
    const int x = tid & 31, y = tid >> 5;
    const int c0 = bx * 32, r0 = by * 32;
    #pragma unroll
    for (int i = 0; i < 4; ++i)
        smem[(y + 8 * i) * 33 + x] = s[(size_t)(r0 + y + 8 * i) * C + c0 + x];
    __syncthreads();
    #pragma unroll
    for (int i = 0; i < 4; ++i)
        d[(size_t)(c0 + y + 8 * i) * R + r0 + x] = (__bf16)smem[x * 33 + (y + 8 * i)];
}

// ---------------------------------------------------------------------------
// prep_kernel: unchanged from best-measured version.
// ---------------------------------------------------------------------------
__global__ __launch_bounds__(256) void prep_kernel(
    const float* __restrict__ Hj, const float* __restrict__ Hi,
    const float* __restrict__ Wpj, const float* __restrict__ Wpi,
    const float* __restrict__ Wv1, const float* __restrict__ Wv2,
    float* __restrict__ Zj, float* __restrict__ Zi,
    __bf16* __restrict__ HiT, __bf16* __restrict__ Wv1T,
    __bf16* __restrict__ Wv2T, __bf16* __restrict__ Acat)
{
    __shared__ float smem[1088];
    const int bid = blockIdx.x;
    const int tid = threadIdx.x;

    if (bid < 4096) {
        const int row = bid & 2047;
        const int which = bid >> 11;
        const float* src = (which ? Hi : Hj) + (size_t)row * Hh;
        const float* W = which ? Wpi : Wpj;
        float* Z = which ? Zi : Zj;
        float* rowbuf = smem;            // [768]
        float* partial = smem + 768;     // [8][24]
        for (int i = tid; i < Hh; i += 256) rowbuf[i] = src[i];
        __syncthreads();
        if (tid < 192) {
            const int d = tid % Dd;
            const int c = tid / Dd;
            const int h0 = c * 96;
            float s = 0.f;
            #pragma unroll 4
            for (int h = h0; h < h0 + 96; ++h) s = fmaf(rowbuf[h], W[h * Dd + d], s);
            partial[c * Dd + d] = s;
        }
        __syncthreads();
        if (tid < Dd) {
            float s = 0.f;
            #pragma unroll
            for (int c = 0; c < 8; ++c) s += partial[c * Dd + tid];
            Z[(size_t)row * Dd + tid] = s;
        }
    } else if (bid < 5632) {
        int rem = bid - 4096;
        const int bz = rem / 384; rem %= 384;
        transpose_tile(Hi + (size_t)bz * Ss * Hh, HiT + (size_t)bz * Hh * Ss,
                       Ss, Hh, rem % 24, rem / 24, smem, tid);
    } else if (bid < 7360) {
        const int rem = bid - 5632;
        transpose_tile(Wv1, Wv1T, 3 * Hh, Oo, rem % 24, rem / 24, smem, tid);
    } else if (bid < 7936) {
        const int rem = bid - 7360;
        transpose_tile(Wv2, Wv2T, Oo, Hh, rem % 24, rem / 24, smem, tid);
    } else {
        const int idx = (bid - 7936) * 256 + tid;   // [0, 2048*96)
        const int row = idx / 96, c8 = idx % 96;
        const float* s = Hj + (size_t)row * Hh + c8 * 8;
        const float4 u = *(const float4*)s;
        const float4 v = *(const float4*)(s + 4);
        bf16x8 o;
        o[0]=(__bf16)u.x; o[1]=(__bf16)u.y; o[2]=(__bf16)u.z; o[3]=(__bf16)u.w;
        o[4]=(__bf16)v.x; o[5]=(__bf16)v.y; o[6]=(__bf16)v.z; o[7]=(__bf16)v.w;
        *(bf16x8*)&Acat[(size_t)row * 2304 + Hh + c8 * 8] = o;
    }
}

// ---------------------------------------------------------------------------
// Kernel B (MFMA): unchanged from best-measured version.
// ---------------------------------------------------------------------------
__global__ __launch_bounds__(256) void pair_kernel(
    const float* __restrict__ Zj, const float* __restrict__ Zi,
    const float* __restrict__ Ws1, const float* __restrict__ bs1,
    const float* __restrict__ ws2, const float* __restrict__ bs2p,
    const int* __restrict__ mask, __bf16* __restrict__ probs)
{
    const int bp = blockIdx.x;
    const int b  = bp >> 9;              // S = 512
    const int tid  = threadIdx.x;
    const int lane = tid & 63;
    const int wid  = tid >> 6;
    const int col  = lane & 15;
    const int g    = lane >> 4;

    __shared__ float zjall[Dd];
    __shared__ float rowadd[Mm];
    __shared__ float logitsl[Ss];
    __shared__ float red[8];

    if (tid < Dd) zjall[tid] = Zj[(size_t)bp * Dd + tid];
    __syncthreads();
    if (tid < Mm) {
        float s = bs1[tid];
        #pragma unroll
        for (int d = 0; d < Dd; ++d) s = fmaf(zjall[d], Ws1[d * Mm + tid], s);
        rowadd[tid] = s;
    }
    __syncthreads();

    float zj8[8];
    if (g < 3) {
        const float* zr = Zj + (size_t)bp * Dd + g * 8;
        const float4 u = *(const float4*)zr;
        const float4 v = *(const float4*)(zr + 4);
        zj8[0]=u.x; zj8[1]=u.y; zj8[2]=u.z; zj8[3]=u.w;
        zj8[4]=v.x; zj8[5]=v.y; zj8[6]=v.z; zj8[7]=v.w;
    } else {
        #pragma unroll
        for (int j = 0; j < 8; ++j) zj8[j] = 0.f;
    }

    bf16x8 bw[6][2];
    float ws2r[6];
    #pragma unroll
    for (int n = 0; n < 6; ++n) {
        const int m = n * 16 + col;
        ws2r[n] = ws2[m];
        bf16x8 b0, b1;
        if (g < 3) {
            #pragma unroll
            for (int j = 0; j < 8; ++j) {
                const int d = g * 8 + j;
                b0[j] = (__bf16)(fmaf(zj8[j], Ws1[(2 * Dd + d) * Mm + m],
                                      Ws1[(Dd + d) * Mm + m]));
                b1[j] = (__bf16)(Ws1[(3 * Dd + d) * Mm + m]);
            }
        } else {
            #pragma unroll
            for (int j = 0; j < 8; ++j) { b0[j] = (__bf16)0.f; b1[j] = (__bf16)0.f; }
            b0[0] = (__bf16)rowadd[m];
        }
        bw[n][0] = b0; bw[n][1] = b1;
    }

    const float* zib = Zi + (size_t)b * Ss * Dd;

    #pragma unroll 2
    for (int t = 0; t < 8; ++t) {
        const int q0 = wid * 128 + t * 16;
        bf16x8 a0, a1;
        if (g < 3) {
            const float* zr = zib + (size_t)(q0 + col) * Dd + g * 8;
            const float4 u = *(const float4*)zr;
            const float4 v = *(const float4*)(zr + 4);
            a0[0]=(__bf16)u.x; a0[1]=(__bf16)u.y; a0[2]=(__bf16)u.z; a0[3]=(__bf16)u.w;
            a0[4]=(__bf16)v.x; a0[5]=(__bf16)v.y; a0[6]=(__bf16)v.z; a0[7]=(__bf16)v.w;
            a1[0]=(__bf16)fabsf(zj8[0]-u.x); a1[1]=(__bf16)fabsf(zj8[1]-u.y);
            a1[2]=(__bf16)fabsf(zj8[2]-u.z); a1[3]=(__bf16)fabsf(zj8[3]-u.w);
            a1[4]=(__bf16)fabsf(zj8[4]-v.x); a1[5]=(__bf16)fabsf(zj8[5]-v.y);
            a1[6]=(__bf16)fabsf(zj8[6]-v.z); a1[7]=(__bf16)fabsf(zj8[7]-v.w);
        } else {
            #pragma unroll
            for (int j = 0; j < 8; ++j) { a0[j] = (__bf16)0.f; a1[j] = (__bf16)0.f; }
            a0[0] = (__bf16)1.0f;
        }

        f32x4 acc[6];
        #pragma unroll
        for (int n = 0; n < 6; ++n) acc[n] = (f32x4){0.f, 0.f, 0.f, 0.f};
        #pragma unroll
        for (int n = 0; n < 6; ++n) {
            acc[n] = __builtin_amdgcn_mfma_f32_16x16x32_bf16(a0, bw[n][0], acc[n], 0, 0, 0);
            acc[n] = __builtin_amdgcn_mfma_f32_16x16x32_bf16(a1, bw[n][1], acc[n], 0, 0, 0);
        }

        float lsum[4] = {0.f, 0.f, 0.f, 0.f};
        #pragma unroll
        for (int n = 0; n < 6; ++n)
            #pragma unroll
            for (int r = 0; r < 4; ++r)
                lsum[r] = fmaf(fmaxf(acc[n][r], 0.f), ws2r[n], lsum[r]);
        #pragma unroll
        for (int off = 1; off <= 8; off <<= 1) {
            #pragma unroll
            for (int r = 0; r < 4; ++r) lsum[r] += __shfl_xor(lsum[r], off);
        }
        if (col == 0) {
            float4 o = {lsum[0], lsum[1], lsum[2], lsum[3]};
            *(float4*)&logitsl[q0 + g * 4] = o;
        }
    }
    __syncthreads();

    const float bs2v = bs2p[0];
    const int* mrow = mask + (size_t)b * Ss;
    float l0 = logitsl[tid]       + bs2v + (1.0f - (float)mrow[tid])       * (-3.402823466e+38f);
    float l1 = logitsl[tid + 256] + bs2v + (1.0f - (float)mrow[tid + 256]) * (-3.402823466e+38f);
    float vmax = fmaxf(l0, l1);
    #pragma unroll
    for (int off = 32; off > 0; off >>= 1) vmax = fmaxf(vmax, __shfl_xor(vmax, off));
    if (lane == 0) red[wid] = vmax;
    __syncthreads();
    const float mx = fmaxf(fmaxf(red[0], red[1]), fmaxf(red[2], red[3]));
    const float e0 = __expf(l0 - mx);
    const float e1 = __expf(l1 - mx);
    float vs = e0 + e1;
    #pragma unroll
    for (int off = 32; off > 0; off >>= 1) vs += __shfl_xor(vs, off);
    if (lane == 0) red[4 + wid] = vs;
    __syncthreads();
    const float inv = 1.0f / (red[4] + red[5] + red[6] + red[7]);
    __bf16* prow = probs + (size_t)bp * Ss;
    prow[tid] = (__bf16)(e0 * inv);
    prow[tid + 256] = (__bf16)(e1 * inv);
}

// ---------------------------------------------------------------------------
// NEW GEMM: 64x96 tile, BK=64, global_load_lds(16B) staging, triple-buffered
// LDS with counted vmcnt(5) + ONE raw s_barrier per K-step (T3/T4 minimum
// pipeline). LDS is written linearly by global_load_lds; bank conflicts on
// ds_read_b128 avoided by both-sides XOR swizzle (source col k16 ^= row&7,
// same XOR on read). Grid = 32x8 = 256 blocks (1/CU, perfect coverage).
// MODE 0: ctx -> Acat seg0 & seg2.  MODE 1: mhid = relu(Acat@Wv1T + bv1).
// MODE 2: out = alpha*(mhid@Wv2T + bv2).
// ---------------------------------------------------------------------------
__device__ __forceinline__ void gload16(const __bf16* g, __bf16* l)
{
    __builtin_amdgcn_global_load_lds(
        (const __attribute__((address_space(1))) void*)g,
        (__attribute__((address_space(3))) void*)l, 16, 0, 0);
}

__device__ __forceinline__ int swz(int row, int k)
{
    // element offset into a [rows][64] bf16 tile, XOR-swizzled in 8-elem (16B)
    // units: slot = (k/8) ^ (row&7)
    return row * 64 + (k ^ ((row & 7) << 3));
}

template<int MODE>
__global__ __launch_bounds__(256) void gemm_kernel(
    const __bf16* __restrict__ A, const __bf16* __restrict__ Bt,
    const float* __restrict__ Hjf, const float* __restrict__ bias,
    const float* __restrict__ alphap,
    __bf16* __restrict__ obf, float* __restrict__ of)
{
    constexpr int K = (MODE == 0) ? 512 : (MODE == 1) ? 2304 : 768;
    constexpr int NIT = K / 64;

    __shared__ __align__(16) __bf16 As[3][64 * 64];   // 24 KB
    __shared__ __align__(16) __bf16 Bs[3][96 * 64];   // 36 KB

    const int tid = threadIdx.x;
    const int lane = tid & 63;
    const int wid = tid >> 6;
    const int col = lane & 15, g = lane >> 4;
    const int wm = wid >> 1, wn = wid & 1;     // 2x2 wave grid, wave = 32x48
    const int r0 = blockIdx.x * 64;
    const int n0 = blockIdx.y * 96;
    const __bf16* Btb = (MODE == 0) ? Bt + (size_t)(r0 >> 9) * (Hh * Ss) : Bt;

    // ---- staging descriptors.  A-tile: 64x64 bf16 = 512 16B-chunks -> 8
    // wave-instrs (2/wave).  B-tile: 96x64 = 768 chunks -> 12 instrs (3/wave).
    // chunk c -> (row = c>>3, k16 = c&7); source col pre-swizzled so the
    // linear LDS write lands the swizzled layout.
    const __bf16* asrc[2];
    const __bf16* bsrc[3];
    int aldo[2], bldo[3];
    #pragma unroll
    for (int i = 0; i < 2; ++i) {
        const int c = (wid * 2 + i) * 64 + lane;
        const int row = c >> 3;
        const int k16 = (c & 7) ^ (row & 7);
        asrc[i] = A + (size_t)(r0 + row) * K + k16 * 8;
        aldo[i] = (wid * 2 + i) * 512;             // 64 chunks * 8 elems
    }
    #pragma unroll
    for (int i = 0; i < 3; ++i) {
        const int c = (wid * 3 + i) * 64 + lane;
        const int row = c >> 3;
        const int k16 = (c & 7) ^ (row & 7);
        bsrc[i] = Btb + (size_t)(n0 + row) * K + k16 * 8;
        bldo[i] = (wid * 3 + i) * 512;
    }

    auto stage = [&](int t, int buf) {
        __bf16* ab = &As[buf][0];
        __bf16* bb = &Bs[buf][0];
        #pragma unroll
        for (int i = 0; i < 2; ++i) gload16(asrc[i] + (size_t)t * 64, ab + aldo[i]);
        #pragma unroll
        for (int i = 0; i < 3; ++i) gload16(bsrc[i] + (size_t)t * 64, bb + bldo[i]);
    };

    f32x4 acc[2][3];
    #pragma unroll
    for (int mi = 0; mi < 2; ++mi)
        #pragma unroll
        for (int ni = 0; ni < 3; ++ni) acc[mi][ni] = (f32x4){0.f, 0.f, 0.f, 0.f};

    stage(0, 0);
    stage(1, 1);

    for (int it = 0; it < NIT; ++it) {
        // wait for buf[it%3]'s 5 loads (leave the newest 5 — next tile — in
        // flight); all waves join, THEN issue the t+2 prefetch.
        if (it < NIT - 1) asm volatile("s_waitcnt vmcnt(5)" ::: "memory");
        else              asm volatile("s_waitcnt vmcnt(0)" ::: "memory");
        __builtin_amdgcn_s_barrier();
        __builtin_amdgcn_sched_barrier(0);
        if (it + 2 < NIT) stage(it + 2, (it + 2) % 3);

        const __bf16* Ac = As[it % 3];
        const __bf16* Bc = Bs[it % 3];
        #pragma unroll
        for (int h = 0; h < 2; ++h) {
            const int ka = h * 32 + g * 8;
            const bf16x8 a0 = *(const bf16x8*)&Ac[swz(wm * 32 +      col, ka)];
            const bf16x8 a1 = *(const bf16x8*)&Ac[swz(wm * 32 + 16 + col, ka)];
            const bf16x8 b0 = *(const bf16x8*)&Bc[swz(wn * 48 +      col, ka)];
            const bf16x8 b1 = *(const bf16x8*)&Bc[swz(wn * 48 + 16 + col, ka)];
            const bf16x8 b2 = *(const bf16x8*)&Bc[swz(wn * 48 + 32 + col, ka)];
            acc[0][0] = __builtin_amdgcn_mfma_f32_16x16x32_bf16(a0, b0, acc[0][0], 0, 0, 0);
            acc[0][1] = __builtin_amdgcn_mfma_f32_16x16x32_bf16(a0, b1, acc[0][1], 0, 0, 0);
            acc[0][2] = __builtin_amdgcn_mfma_f32_16x16x32_bf16(a0, b2, acc[0][2], 0, 0, 0);
            acc[1][0] = __builtin_amdgcn_mfma_f32_16x16x32_bf16(a1, b0, acc[1][0], 0, 0, 0);
            acc[1][1] = __builtin_amdgcn_mfma_f32_16x16x32_bf16(a1, b1, acc[1][1], 0, 0, 0);
            acc[1][2] = __builtin_amdgcn_mfma_f32_16x16x32_bf16(a1, b2, acc[1][2], 0, 0, 0);
        }
    }

    const float al = (MODE == 2) ? alphap[0] : 0.f;
    #pragma unroll
    for (int mi = 0; mi < 2; ++mi) {
        #pragma unroll
        for (int r = 0; r < 4; ++r) {
            const int row = r0 + wm * 32 + mi * 16 + g * 4 + r;
            #pragma unroll
            for (int ni = 0; ni < 3; ++ni) {
                const int cn = n0 + wn * 48 + ni * 16 + col;
                const float v = acc[mi][ni][r];
                if (MODE == 0) {
                    const float hjv = Hjf[(size_t)row * Hh + cn];
                    obf[(size_t)row * 2304 + cn] = (__bf16)v;
                    obf[(size_t)row * 2304 + 1536 + cn] = (__bf16)(v * hjv);
                } else if (MODE == 1) {
                    obf[(size_t)row * Oo + cn] = (__bf16)fmaxf(v + bias[cn], 0.f);
                } else {
                    of[(size_t)row * Hh + cn] = al * (v + bias[cn]);
                }
            }
        }
    }
}

// ---------------------------------------------------------------------------
extern "C" void kernel_launch(void* const* d_in, const int* in_sizes, int n_in,
                              void* d_out, int out_size, void* d_ws, size_t ws_size,
                              hipStream_t stream)
{
    const float* Hj  = (const float*)d_in[0];
    const float* Hi  = (const float*)d_in[1];
    const float* Wpj = (const float*)d_in[2];
    const float* Wpi = (const float*)d_in[3];
    const float* Ws1 = (const float*)d_in[4];
    const float* bs1 = (const float*)d_in[5];
    const float* ws2 = (const float*)d_in[6];
    const float* bs2 = (const float*)d_in[7];
    const float* Wv1 = (const float*)d_in[8];
    const float* bv1 = (const float*)d_in[9];
    const float* Wv2 = (const float*)d_in[10];
    const float* bv2 = (const float*)d_in[11];
    const float* alpha = (const float*)d_in[12];
    const int* mask  = (const int*)d_in[13];

    // workspace (float units) — all regions DISTINCT (no lifetime overlays)
    float* ws = (float*)d_ws;
    float* Zj      = ws;                  // 49152
    float* Zi      = Zj + 49152;          // 49152
    float* probs_f = Zi + 49152;          // 524288
    float* HiT_f   = probs_f + 524288;    // 786432
    float* Wv2T_f  = HiT_f + 786432;      // 294912
    float* mhid_f  = Wv2T_f + 294912;     // 786432
    float* Acat_f  = mhid_f + 786432;     // 2359296
    float* Wv1T_f  = Acat_f + 2359296;    // 884736
    // total 5,734,400 floats = 22.9 MB

    __bf16* probs_bf = (__bf16*)probs_f;  // [2048][512]
    __bf16* HiT      = (__bf16*)HiT_f;    // [4][768][512]
    __bf16* Wv2T     = (__bf16*)Wv2T_f;   // [768][768]
    __bf16* mhid_bf  = (__bf16*)mhid_f;   // [2048][768]
    __bf16* Acat     = (__bf16*)Acat_f;   // [2048][2304]
    __bf16* Wv1T     = (__bf16*)Wv1T_f;   // [768][2304]

    prep_kernel<<<dim3(8704), 256, 0, stream>>>(
        Hj, Hi, Wpj, Wpi, Wv1, Wv2, Zj, Zi, HiT, Wv1T, Wv2T, Acat);
    pair_kernel<<<dim3(Bb * Ss), 256, 0, stream>>>(
        Zj, Zi, Ws1, bs1, ws2, bs2, mask, probs_bf);
    gemm_kernel<0><<<dim3(2048 / 64, Hh / 96), 256, 0, stream>>>(
        probs_bf, HiT, Hj, nullptr, nullptr, Acat, nullptr);
    gemm_kernel<1><<<dim3(2048 / 64, Oo / 96), 256, 0, stream>>>(
        Acat, Wv1T, nullptr, bv1, nullptr, mhid_bf, nullptr);
    gemm_kernel<2><<<dim3(2048 / 64, Hh / 96), 256, 0, stream>>>(
        mhid_bf, Wv2T, nullptr, bv2, alpha, nullptr, (float*)d_out);
}